// Round 2
// baseline (464.242 us; speedup 1.0000x reference)
//
#include <hip/hip_runtime.h>

// Problem dims
#define B_   16
#define M_   2048
#define D_   128
#define H_   256
#define K_   64
#define ROWS (B_ * M_)   // 32768

typedef short short8 __attribute__((ext_vector_type(8)));
typedef short short4v __attribute__((ext_vector_type(4)));
typedef float f32x4  __attribute__((ext_vector_type(4)));

// ws layout (in short/bf16 elements)
// Q stored hi+lo (removes q-side rounding); K stored hi only (error budget:
// k-rounding alone -> absmax ~5e-3 vs 1.55e-2 threshold, measured r3).
static constexpr size_t OFF_QHI = 0;                           // [ROWS][64]
static constexpr size_t OFF_QLO = (size_t)ROWS * K_;
static constexpr size_t OFF_KHI = 2 * (size_t)ROWS * K_;
static constexpr size_t OFF_W1H = 3 * (size_t)ROWS * K_;       // [2][H_][D_]
static constexpr size_t OFF_W1L = OFF_W1H + 2 * (size_t)D_ * H_;
static constexpr size_t OFF_W2H = OFF_W1L + 2 * (size_t)D_ * H_;  // [2][K_][H_]
static constexpr size_t OFF_W2L = OFF_W2H + 2 * (size_t)H_ * K_;

static __device__ __forceinline__ float bf2f(short u) {
    union { unsigned int u; float f; } c;
    c.u = ((unsigned int)(unsigned short)u) << 16;
    return c.f;
}
static __device__ __forceinline__ short f2bf(float f) {
    union { float f; unsigned int u; } c; c.f = f;
    unsigned int u = c.u + 0x7fffu + ((c.u >> 16) & 1u);   // RNE
    return (short)(u >> 16);
}
static __device__ __forceinline__ void split2(float v, short& hi, short& lo) {
    hi = f2bf(v);
    lo = f2bf(v - bf2f(hi));
}
static __device__ __forceinline__ f32x4 mfma16(short8 a, short8 b, f32x4 c) {
    return __builtin_amdgcn_mfma_f32_16x16x32_bf16(a, b, c, 0, 0, 0);
}

// ---------------------------------------------------------------------------
// k0: transpose + hi/lo split weights (fp32 -> bf16 planes)
// ---------------------------------------------------------------------------
__global__ __launch_bounds__(256) void prep_w(
    const float* __restrict__ qW1, const float* __restrict__ kW1,
    const float* __restrict__ qW2, const float* __restrict__ kW2,
    short* __restrict__ ws)
{
    const int which = blockIdx.y;
    const float* src; short* dhi; short* dlo; int N, Kd;
    if (which == 0)      { src = qW1; dhi = ws + OFF_W1H;            dlo = ws + OFF_W1L;            N = H_; Kd = D_; }
    else if (which == 1) { src = kW1; dhi = ws + OFF_W1H + D_ * H_;  dlo = ws + OFF_W1L + D_ * H_;  N = H_; Kd = D_; }
    else if (which == 2) { src = qW2; dhi = ws + OFF_W2H;            dlo = ws + OFF_W2L;            N = K_; Kd = H_; }
    else                 { src = kW2; dhi = ws + OFF_W2H + H_ * K_;  dlo = ws + OFF_W2L + H_ * K_;  N = K_; Kd = H_; }
    int idx = blockIdx.x * 256 + threadIdx.x;
    if (idx < N * Kd) {
        int n = idx / Kd, k = idx % Kd;
        float v = src[(size_t)k * N + n];   // dst[n][k] = src[k][n]
        short hi, lo; split2(v, hi, lo);
        dhi[idx] = hi; dlo[idx] = lo;
    }
}

// ---------------------------------------------------------------------------
// k1: fused MLP per wave (16 rows), fp32 in, split-bf16 MFMA arithmetic.
//   head 0 -> Q hi+lo planes; head 1 -> K hi plane only.
// Block = 128 thr (2 waves). grid = (ROWS/32, 2 heads).
//
// OPERAND-SWAPPED GEMMs (R2): mfma(Wfrag, xfrag) puts the weight's free
// index on (quad,reg) and the row index m on l15, so each lane owns
// 4 CONSECUTIVE output columns of ONE row. GEMM1 epilogue becomes a
// float4 bias load + packed short4 ds_write_b64 per plane (was 8 scalar
// ds_write_b16); GEMM2 output becomes packed b64 global stores (was 8
// scalar b16). Fragment loads are unchanged (A/B frag lane layouts are
// identical); same 3 products in the same order per accumulator ->
// bitwise-identical numerics vs the verified version.
// ---------------------------------------------------------------------------
__global__ __launch_bounds__(128) void mlp_kernel(
    const float* __restrict__ x,     // [ROWS][128] fp32
    short* __restrict__ ws,
    const float* __restrict__ qb1, const float* __restrict__ kb1,
    const float* __restrict__ qb2, const float* __restrict__ kb2)
{
    const int head = blockIdx.y;
    const short* W1H = ws + OFF_W1H + (size_t)head * (D_ * H_);  // [256][128]
    const short* W1L = ws + OFF_W1L + (size_t)head * (D_ * H_);
    const short* W2H = ws + OFF_W2H + (size_t)head * (H_ * K_);  // [64][256]
    const short* W2L = ws + OFF_W2L + (size_t)head * (H_ * K_);
    const float* b1  = head ? kb1 : qb1;
    const float* b2  = head ? kb2 : qb2;
    short* ohi       = ws + (head ? OFF_KHI : OFF_QHI);          // [ROWS][64]
    short* olo       = ws + OFF_QLO;                             // head 0 only

    const int tid  = threadIdx.x;
    const int w    = tid >> 6;        // wave 0..1
    const int lane = tid & 63;
    const int l15  = lane & 15;
    const int quad = lane >> 4;
    const int r0   = (blockIdx.x * 2 + w) * 16;   // this wave's 16 rows

    // per-wave h tile [m=16][hcol=256], hi/lo planes; row stride 264 shorts.
    // Writes: b64 at word base (4*l15 + 2*quad + 8*jt)%32 -> exactly 4
    // bank-cycles (conflict-free min). Reads: b128 at (4*(l15+quad')+16ks)%32
    // -> exactly 8 bank-cycles (conflict-free min).
    __shared__ __align__(16) short hsh[2][16][264];
    __shared__ __align__(16) short hsl[2][16][264];

    // ---- A-frags from x: A[m=l15][k=quad*8+j], split hi/lo; float4 loads ----
    short8 ah[4], al[4];
    const float* xrow = x + (size_t)(r0 + l15) * D_ + quad * 8;
    #pragma unroll
    for (int ks = 0; ks < 4; ++ks) {
        float4 v0 = *(const float4*)(xrow + ks * 32);
        float4 v1 = *(const float4*)(xrow + ks * 32 + 4);
        float vv[8] = {v0.x, v0.y, v0.z, v0.w, v1.x, v1.y, v1.z, v1.w};
        #pragma unroll
        for (int j = 0; j < 8; ++j) {
            short hi, lo; split2(vv[j], hi, lo);
            ah[ks][j] = hi; al[ks][j] = lo;
        }
    }

    // ---- GEMM1 (swapped): lane -> h[m=l15][hcol = jt*16 + quad*4 + r] ----
    #pragma unroll
    for (int jt = 0; jt < 16; ++jt) {             // 16 col-tiles of H=256
        f32x4 acc = {0.f, 0.f, 0.f, 0.f};
        const size_t wro = (size_t)(jt * 16 + l15) * D_ + quad * 8;
        #pragma unroll
        for (int ks = 0; ks < 4; ++ks) {
            short8 bh = *(const short8*)(W1H + wro + ks * 32);
            short8 bl = *(const short8*)(W1L + wro + ks * 32);
            acc = mfma16(bh, ah[ks], acc);   // == ah·bh transposed
            acc = mfma16(bh, al[ks], acc);   // == al·bh
            acc = mfma16(bl, ah[ks], acc);   // == ah·bl
        }
        float4 bias4 = *(const float4*)(b1 + jt * 16 + quad * 4);
        short4v hi4, lo4;
        #pragma unroll
        for (int r = 0; r < 4; ++r) {
            float v = acc[r] + ((const float*)&bias4)[r];
            v = v > 0.f ? v : 0.f;
            short hi, lo; split2(v, hi, lo);
            hi4[r] = hi; lo4[r] = lo;
        }
        *(short4v*)&hsh[w][l15][jt * 16 + quad * 4] = hi4;
        *(short4v*)&hsl[w][l15][jt * 16 + quad * 4] = lo4;
    }
    // no barrier: each wave reads only its own LDS region

    // ---- GEMM2: A-frags from hs (same frag layout as before) ----
    short8 gh[8], gl[8];
    #pragma unroll
    for (int ks = 0; ks < 8; ++ks) {
        gh[ks] = *(const short8*)&hsh[w][l15][ks * 32 + quad * 8];
        gl[ks] = *(const short8*)&hsl[w][l15][ks * 32 + quad * 8];
    }
    #pragma unroll
    for (int jt = 0; jt < 4; ++jt) {              // 4 col-tiles of K=64
        f32x4 acc = {0.f, 0.f, 0.f, 0.f};
        const size_t wro = (size_t)(jt * 16 + l15) * H_ + quad * 8;
        #pragma unroll
        for (int ks = 0; ks < 8; ++ks) {
            short8 bh = *(const short8*)(W2H + wro + ks * 32);
            short8 bl = *(const short8*)(W2L + wro + ks * 32);
            acc = mfma16(bh, gh[ks], acc);   // == gh·bh
            acc = mfma16(bh, gl[ks], acc);   // == gl·bh
            acc = mfma16(bl, gh[ks], acc);   // == gh·bl
        }
        float4 bias4 = *(const float4*)(b2 + jt * 16 + quad * 4);
        // lane -> out[m = r0+l15][kcol = jt*16 + quad*4 + r], packed b64
        const size_t oi = (size_t)(r0 + l15) * K_ + jt * 16 + quad * 4;
        if (head == 0) {
            short4v hi4, lo4;
            #pragma unroll
            for (int r = 0; r < 4; ++r) {
                float v = acc[r] + ((const float*)&bias4)[r];
                short hi, lo; split2(v, hi, lo);
                hi4[r] = hi; lo4[r] = lo;
            }
            *(short4v*)(ohi + oi) = hi4;
            *(short4v*)(olo + oi) = lo4;
        } else {
            short4v hi4;
            #pragma unroll
            for (int r = 0; r < 4; ++r)
                hi4[r] = f2bf(acc[r] + ((const float*)&bias4)[r]);
            *(short4v*)(ohi + oi) = hi4;
        }
    }
}

// ---------------------------------------------------------------------------
// k2: scores + max-division softmax. Block = 512 thr (8 waves), 16 Q-rows.
// 1D grid 2048, XCD-swizzled: xcd = flat&7 serves batches {xcd, xcd+8} only
// -> per-XCD L2 working set ~2 MB (K+Q of 2 batches), L2-resident re-reads.
// __launch_bounds__(512,4): VGPR cap 128 -> 2 blocks/CU so one block's
// store phase overlaps the next block's load/MFMA phase.
//
// OPERAND-SWAPPED MFMA: compute mfma(K_frag, Q_frag) so each lane owns 4
// consecutive output columns of a single row -> f32x4 nt stores + scalar
// row stats. (R1: measured neutral vs scalar stores -> not store-bound.)
// ---------------------------------------------------------------------------
__global__ __launch_bounds__(512, 4) void scores_kernel(
    const short* __restrict__ ws,
    float* __restrict__ out)          // [B][M][M] fp32
{
    const int flat = blockIdx.x;
    const int xcd  = flat & 7;
    const int slot = flat >> 3;
    const int bb   = (slot & 1) * 8 + xcd;   // batch
    const int i0   = (slot >> 1) * 16;       // Q-row tile
    const int tid  = threadIdx.x;
    const int w    = tid >> 6;        // wave 0..7
    const int lane = tid & 63;
    const int l15  = lane & 15;
    const int quad = lane >> 4;

    const short* Qh = ws + OFF_QHI + (size_t)bb * M_ * K_;
    const short* Ql = ws + OFF_QLO + (size_t)bb * M_ * K_;
    const short* Kh = ws + OFF_KHI + (size_t)bb * M_ * K_;

    // Q B-frags for rows i0..i0+15 (B-operand row = l15 = i offset)
    const size_t qo = (size_t)(i0 + l15) * K_ + quad * 8;
    short8 qh0 = *(const short8*)(Qh + qo);
    short8 qh1 = *(const short8*)(Qh + qo + 32);
    short8 ql0 = *(const short8*)(Ql + qo);
    short8 ql1 = *(const short8*)(Ql + qo + 32);

    // s[t][r] = S[i0+l15][(w*16+t)*16 + quad*4 + r]
    f32x4 s[16];
    #pragma unroll
    for (int t = 0; t < 16; ++t) {
        const int j0 = (w * 16 + t) * 16;
        const size_t ko = (size_t)(j0 + l15) * K_ + quad * 8;
        short8 kh0 = *(const short8*)(Kh + ko);
        short8 kh1 = *(const short8*)(Kh + ko + 32);
        f32x4 acc = {0.f, 0.f, 0.f, 0.f};
        acc = mfma16(kh0, qh0, acc);   // A=K (rows j), B=Q (rows i)
        acc = mfma16(kh0, ql0, acc);
        acc = mfma16(kh1, qh1, acc);
        acc = mfma16(kh1, ql1, acc);
        s[t] = acc;
    }

    // ---- row max & min (row = i0+l15, one row per lane) ----
    f32x4 vmx = s[0], vmn = s[0];
    #pragma unroll
    for (int t = 1; t < 16; ++t)
        #pragma unroll
        for (int r = 0; r < 4; ++r) {
            vmx[r] = fmaxf(vmx[r], s[t][r]);
            vmn[r] = fminf(vmn[r], s[t][r]);
        }
    float mx = fmaxf(fmaxf(vmx[0], vmx[1]), fmaxf(vmx[2], vmx[3]));
    float mn = fminf(fminf(vmn[0], vmn[1]), fminf(vmn[2], vmn[3]));
    // reduce across quads (lanes l15, l15+16, l15+32, l15+48 share a row)
    mx = fmaxf(mx, __shfl_xor(mx, 16));  mn = fminf(mn, __shfl_xor(mn, 16));
    mx = fmaxf(mx, __shfl_xor(mx, 32));  mn = fminf(mn, __shfl_xor(mn, 32));

    __shared__ float redmax[8][16], redmin[8][16], redsum[8][16];
    if (lane < 16) { redmax[w][l15] = mx; redmin[w][l15] = mn; }
    __syncthreads();

    float mm = redmax[0][l15], nn = redmin[0][l15];
    #pragma unroll
    for (int ww = 1; ww < 8; ++ww) {
        mm = fmaxf(mm, redmax[ww][l15]);
        nn = fminf(nn, redmin[ww][l15]);
    }
    const float inv = 1.0f / mm;
    // z = qkt/rmax; true max of z = max(1, rmin/rmax) (handles rmax<0)
    const float nz  = -fmaxf(1.0f, nn * inv);

    // ---- exp(z - zmax) in place + row sum ----
    float lsum = 0.f;
    #pragma unroll
    for (int t = 0; t < 16; ++t)
        #pragma unroll
        for (int r = 0; r < 4; ++r) {
            float e = __expf(fmaf(s[t][r], inv, nz));
            s[t][r] = e;
            lsum += e;
        }
    lsum += __shfl_xor(lsum, 16);
    lsum += __shfl_xor(lsum, 32);
    if (lane < 16) redsum[w][l15] = lsum;
    __syncthreads();

    float tot = 0.f;
    #pragma unroll
    for (int ww = 0; ww < 8; ++ww) tot += redsum[ww][l15];
    const float invsum = 1.0f / tot;

    // ---- normalize + vectorized nontemporal store fp32 ----
    float* ob = out + (size_t)bb * M_ * M_ + (size_t)(i0 + l15) * M_;
    #pragma unroll
    for (int t = 0; t < 16; ++t) {
        f32x4 v;
        #pragma unroll
        for (int r = 0; r < 4; ++r) v[r] = s[t][r] * invsum;
        __builtin_nontemporal_store(v, (f32x4*)(ob + (w * 16 + t) * 16 + quad * 4));
    }
}

// ---------------------------------------------------------------------------
extern "C" void kernel_launch(void* const* d_in, const int* in_sizes, int n_in,
                              void* d_out, int out_size, void* d_ws, size_t ws_size,
                              hipStream_t stream)
{
    (void)in_sizes; (void)n_in; (void)out_size; (void)ws_size;
    const float* x   = (const float*)d_in[0];
    const float* qW1 = (const float*)d_in[1];
    const float* qb1 = (const float*)d_in[2];
    const float* qW2 = (const float*)d_in[3];
    const float* qb2 = (const float*)d_in[4];
    const float* kW1 = (const float*)d_in[5];
    const float* kb1 = (const float*)d_in[6];
    const float* kW2 = (const float*)d_in[7];
    const float* kb2 = (const float*)d_in[8];
    short* ws  = (short*)d_ws;
    float* out = (float*)d_out;

    prep_w<<<dim3(128, 4), 256, 0, stream>>>(qW1, kW1, qW2, kW2, ws);
    mlp_kernel<<<dim3(ROWS / 32, 2), 128, 0, stream>>>(x, ws, qb1, kb1, qb2, kb2);
    scores_kernel<<<dim3(2048), 512, 0, stream>>>(ws, out);
}

// Round 3
// 415.025 us; speedup vs baseline: 1.1186x; 1.1186x over previous
//
#include <hip/hip_runtime.h>

// Problem dims
#define B_   16
#define M_   2048
#define D_   128
#define H_   256
#define K_   64
#define ROWS (B_ * M_)   // 32768

typedef short short8 __attribute__((ext_vector_type(8)));
typedef short short4v __attribute__((ext_vector_type(4)));
typedef float f32x4  __attribute__((ext_vector_type(4)));

// ws layout (in short/bf16 elements)
// Q stored hi+lo (removes q-side rounding); K stored hi only (error budget:
// k-rounding alone -> absmax ~5e-3 vs 1.55e-2 threshold, measured r3).
static constexpr size_t OFF_QHI = 0;                           // [ROWS][64]
static constexpr size_t OFF_QLO = (size_t)ROWS * K_;
static constexpr size_t OFF_KHI = 2 * (size_t)ROWS * K_;
static constexpr size_t OFF_W1H = 3 * (size_t)ROWS * K_;       // [2][H_][D_]
static constexpr size_t OFF_W1L = OFF_W1H + 2 * (size_t)D_ * H_;
static constexpr size_t OFF_W2H = OFF_W1L + 2 * (size_t)D_ * H_;  // [2][K_][H_]
static constexpr size_t OFF_W2L = OFF_W2H + 2 * (size_t)H_ * K_;

static __device__ __forceinline__ float bf2f(short u) {
    union { unsigned int u; float f; } c;
    c.u = ((unsigned int)(unsigned short)u) << 16;
    return c.f;
}
static __device__ __forceinline__ short f2bf(float f) {
    union { float f; unsigned int u; } c; c.f = f;
    unsigned int u = c.u + 0x7fffu + ((c.u >> 16) & 1u);   // RNE
    return (short)(u >> 16);
}
static __device__ __forceinline__ void split2(float v, short& hi, short& lo) {
    hi = f2bf(v);
    lo = f2bf(v - bf2f(hi));
}
static __device__ __forceinline__ f32x4 mfma16(short8 a, short8 b, f32x4 c) {
    return __builtin_amdgcn_mfma_f32_16x16x32_bf16(a, b, c, 0, 0, 0);
}

// ---------------------------------------------------------------------------
// k0: transpose + hi/lo split weights (fp32 -> bf16 planes)
// ---------------------------------------------------------------------------
__global__ __launch_bounds__(256) void prep_w(
    const float* __restrict__ qW1, const float* __restrict__ kW1,
    const float* __restrict__ qW2, const float* __restrict__ kW2,
    short* __restrict__ ws)
{
    const int which = blockIdx.y;
    const float* src; short* dhi; short* dlo; int N, Kd;
    if (which == 0)      { src = qW1; dhi = ws + OFF_W1H;            dlo = ws + OFF_W1L;            N = H_; Kd = D_; }
    else if (which == 1) { src = kW1; dhi = ws + OFF_W1H + D_ * H_;  dlo = ws + OFF_W1L + D_ * H_;  N = H_; Kd = D_; }
    else if (which == 2) { src = qW2; dhi = ws + OFF_W2H;            dlo = ws + OFF_W2L;            N = K_; Kd = H_; }
    else                 { src = kW2; dhi = ws + OFF_W2H + H_ * K_;  dlo = ws + OFF_W2L + H_ * K_;  N = K_; Kd = H_; }
    int idx = blockIdx.x * 256 + threadIdx.x;
    if (idx < N * Kd) {
        int n = idx / Kd, k = idx % Kd;
        float v = src[(size_t)k * N + n];   // dst[n][k] = src[k][n]
        short hi, lo; split2(v, hi, lo);
        dhi[idx] = hi; dlo[idx] = lo;
    }
}

// ---------------------------------------------------------------------------
// k1 (R3 restructure): fused MLP, 32 rows per wave (two 16-row tiles T0/T1
// sharing every loaded weight fragment) -> waves 4096->2048, per-row weight
// L2 traffic halved, MFMA:VMEM ratio 1.5->3.0.
// H split into two 128-col phases so the h LDS tile stays 17 KB/wave
// (2 waves/SIMD preserved): per phase {GEMM1 half -> GEMM2 partial-K}.
// Accumulation order per accumulator exactly preserved vs the verified
// kernel (ks-major, {bh*ah, bh*al, bl*ah} per ks) -> bitwise-identical
// numerics; absmax must stay 0.004882812.
// Block = 128 thr (2 waves). grid = (ROWS/64, 2 heads).
// ---------------------------------------------------------------------------
__global__ __launch_bounds__(128) void mlp_kernel(
    const float* __restrict__ x,     // [ROWS][128] fp32
    short* __restrict__ ws,
    const float* __restrict__ qb1, const float* __restrict__ kb1,
    const float* __restrict__ qb2, const float* __restrict__ kb2)
{
    const int head = blockIdx.y;
    const short* W1H = ws + OFF_W1H + (size_t)head * (D_ * H_);  // [256][128]
    const short* W1L = ws + OFF_W1L + (size_t)head * (D_ * H_);
    const short* W2H = ws + OFF_W2H + (size_t)head * (H_ * K_);  // [64][256]
    const short* W2L = ws + OFF_W2L + (size_t)head * (H_ * K_);
    const float* b1  = head ? kb1 : qb1;
    const float* b2  = head ? kb2 : qb2;
    short* ohi       = ws + (head ? OFF_KHI : OFF_QHI);          // [ROWS][64]
    short* olo       = ws + OFF_QLO;                             // head 0 only

    const int tid  = threadIdx.x;
    const int w    = tid >> 6;        // wave 0..1
    const int lane = tid & 63;
    const int l15  = lane & 15;
    const int quad = lane >> 4;
    const int r0   = (blockIdx.x * 2 + w) * 32;   // this wave's 32 rows

    // per-wave, per-tile h half-tile [16 rows][128 cols], hi/lo planes.
    // Row stride 136 shorts (272 B = 17x16B). Bank math: word stride
    // 68 == 4 (mod 32) -> b64 writes 4/bank, b128 reads 8/bank = both at
    // conflict-free minimum (same structure as the verified 264-stride).
    __shared__ __align__(16) short hsh[2][2][16][136];
    __shared__ __align__(16) short hsl[2][2][16][136];

    // ---- A-frags from x for both row tiles; float4 loads + split ----
    short8 ah[2][4], al[2][4];
    #pragma unroll
    for (int t = 0; t < 2; ++t) {
        const float* xrow = x + (size_t)(r0 + t * 16 + l15) * D_ + quad * 8;
        #pragma unroll
        for (int ks = 0; ks < 4; ++ks) {
            float4 v0 = *(const float4*)(xrow + ks * 32);
            float4 v1 = *(const float4*)(xrow + ks * 32 + 4);
            float vv[8] = {v0.x, v0.y, v0.z, v0.w, v1.x, v1.y, v1.z, v1.w};
            #pragma unroll
            for (int j = 0; j < 8; ++j) {
                short hi, lo; split2(vv[j], hi, lo);
                ah[t][ks][j] = hi; al[t][ks][j] = lo;
            }
        }
    }

    // GEMM2 accumulators live across both phases
    f32x4 acc2[2][4];
    #pragma unroll
    for (int t = 0; t < 2; ++t)
        #pragma unroll
        for (int j = 0; j < 4; ++j)
            acc2[t][j] = f32x4{0.f, 0.f, 0.f, 0.f};

    #pragma unroll
    for (int ph = 0; ph < 2; ++ph) {
        // ---- GEMM1 half: h cols [ph*128, ph*128+128) ----
        #pragma unroll
        for (int j = 0; j < 8; ++j) {
            const int jt = ph * 8 + j;
            f32x4 a0 = {0.f, 0.f, 0.f, 0.f};
            f32x4 a1 = {0.f, 0.f, 0.f, 0.f};
            const size_t wro = (size_t)(jt * 16 + l15) * D_ + quad * 8;
            #pragma unroll
            for (int ks = 0; ks < 4; ++ks) {
                short8 bh = *(const short8*)(W1H + wro + ks * 32);
                short8 bl = *(const short8*)(W1L + wro + ks * 32);
                a0 = mfma16(bh, ah[0][ks], a0);
                a0 = mfma16(bh, al[0][ks], a0);
                a0 = mfma16(bl, ah[0][ks], a0);
                a1 = mfma16(bh, ah[1][ks], a1);
                a1 = mfma16(bh, al[1][ks], a1);
                a1 = mfma16(bl, ah[1][ks], a1);
            }
            float4 bias4 = *(const float4*)(b1 + jt * 16 + quad * 4);
            short4v h4, l4;
            #pragma unroll
            for (int r = 0; r < 4; ++r) {
                float v = a0[r] + ((const float*)&bias4)[r];
                v = v > 0.f ? v : 0.f;
                short hi, lo; split2(v, hi, lo);
                h4[r] = hi; l4[r] = lo;
            }
            *(short4v*)&hsh[w][0][l15][j * 16 + quad * 4] = h4;
            *(short4v*)&hsl[w][0][l15][j * 16 + quad * 4] = l4;
            #pragma unroll
            for (int r = 0; r < 4; ++r) {
                float v = a1[r] + ((const float*)&bias4)[r];
                v = v > 0.f ? v : 0.f;
                short hi, lo; split2(v, hi, lo);
                h4[r] = hi; l4[r] = lo;
            }
            *(short4v*)&hsh[w][1][l15][j * 16 + quad * 4] = h4;
            *(short4v*)&hsl[w][1][l15][j * 16 + quad * 4] = l4;
        }
        // wave-local RAW/WAR on hs: compiler inserts lgkmcnt waits; no
        // barrier needed (each wave touches only its own region).

        // ---- GEMM2 partial: contraction cols [ph*128, ph*128+128) ----
        #pragma unroll
        for (int kk = 0; kk < 4; ++kk) {
            short8 g0h = *(const short8*)&hsh[w][0][l15][kk * 32 + quad * 8];
            short8 g0l = *(const short8*)&hsl[w][0][l15][kk * 32 + quad * 8];
            short8 g1h = *(const short8*)&hsh[w][1][l15][kk * 32 + quad * 8];
            short8 g1l = *(const short8*)&hsl[w][1][l15][kk * 32 + quad * 8];
            #pragma unroll
            for (int jt2 = 0; jt2 < 4; ++jt2) {
                const size_t wro2 = (size_t)(jt2 * 16 + l15) * H_ + ph * 128 + kk * 32 + quad * 8;
                short8 bh = *(const short8*)(W2H + wro2);
                short8 bl = *(const short8*)(W2L + wro2);
                acc2[0][jt2] = mfma16(bh, g0h, acc2[0][jt2]);
                acc2[0][jt2] = mfma16(bh, g0l, acc2[0][jt2]);
                acc2[0][jt2] = mfma16(bl, g0h, acc2[0][jt2]);
                acc2[1][jt2] = mfma16(bh, g1h, acc2[1][jt2]);
                acc2[1][jt2] = mfma16(bh, g1l, acc2[1][jt2]);
                acc2[1][jt2] = mfma16(bl, g1h, acc2[1][jt2]);
            }
        }
    }

    // ---- GEMM2 epilogue: both tiles, packed b64 stores ----
    #pragma unroll
    for (int jt2 = 0; jt2 < 4; ++jt2) {
        float4 bias4 = *(const float4*)(b2 + jt2 * 16 + quad * 4);
        #pragma unroll
        for (int t = 0; t < 2; ++t) {
            const size_t oi = (size_t)(r0 + t * 16 + l15) * K_ + jt2 * 16 + quad * 4;
            if (head == 0) {
                short4v hi4, lo4;
                #pragma unroll
                for (int r = 0; r < 4; ++r) {
                    float v = acc2[t][jt2][r] + ((const float*)&bias4)[r];
                    short hi, lo; split2(v, hi, lo);
                    hi4[r] = hi; lo4[r] = lo;
                }
                *(short4v*)(ohi + oi) = hi4;
                *(short4v*)(olo + oi) = lo4;
            } else {
                short4v hi4;
                #pragma unroll
                for (int r = 0; r < 4; ++r)
                    hi4[r] = f2bf(acc2[t][jt2][r] + ((const float*)&bias4)[r]);
                *(short4v*)(ohi + oi) = hi4;
            }
        }
    }
}

// ---------------------------------------------------------------------------
// k2: scores + max-division softmax. Block = 512 thr (8 waves), 16 Q-rows.
// 1D grid 2048, XCD-swizzled: xcd = flat&7 serves batches {xcd, xcd+8} only
// -> per-XCD L2 working set ~2 MB (K+Q of 2 batches), L2-resident re-reads.
// __launch_bounds__(512,4): VGPR cap 128 -> 2 blocks/CU so one block's
// store phase overlaps the next block's load/MFMA phase.
//
// OPERAND-SWAPPED MFMA: each lane owns 4 consecutive output columns of one
// row -> f32x4 nt stores + scalar row stats. (R1: neutral vs scalar stores
// -> store-drain-bound, not issue-bound. Expected: epilogue hides under the
// 268 MB HBM write drain, ~42 us floor.)
// ---------------------------------------------------------------------------
__global__ __launch_bounds__(512, 4) void scores_kernel(
    const short* __restrict__ ws,
    float* __restrict__ out)          // [B][M][M] fp32
{
    const int flat = blockIdx.x;
    const int xcd  = flat & 7;
    const int slot = flat >> 3;
    const int bb   = (slot & 1) * 8 + xcd;   // batch
    const int i0   = (slot >> 1) * 16;       // Q-row tile
    const int tid  = threadIdx.x;
    const int w    = tid >> 6;        // wave 0..7
    const int lane = tid & 63;
    const int l15  = lane & 15;
    const int quad = lane >> 4;

    const short* Qh = ws + OFF_QHI + (size_t)bb * M_ * K_;
    const short* Ql = ws + OFF_QLO + (size_t)bb * M_ * K_;
    const short* Kh = ws + OFF_KHI + (size_t)bb * M_ * K_;

    // Q B-frags for rows i0..i0+15 (B-operand row = l15 = i offset)
    const size_t qo = (size_t)(i0 + l15) * K_ + quad * 8;
    short8 qh0 = *(const short8*)(Qh + qo);
    short8 qh1 = *(const short8*)(Qh + qo + 32);
    short8 ql0 = *(const short8*)(Ql + qo);
    short8 ql1 = *(const short8*)(Ql + qo + 32);

    // s[t][r] = S[i0+l15][(w*16+t)*16 + quad*4 + r]
    f32x4 s[16];
    #pragma unroll
    for (int t = 0; t < 16; ++t) {
        const int j0 = (w * 16 + t) * 16;
        const size_t ko = (size_t)(j0 + l15) * K_ + quad * 8;
        short8 kh0 = *(const short8*)(Kh + ko);
        short8 kh1 = *(const short8*)(Kh + ko + 32);
        f32x4 acc = {0.f, 0.f, 0.f, 0.f};
        acc = mfma16(kh0, qh0, acc);   // A=K (rows j), B=Q (rows i)
        acc = mfma16(kh0, ql0, acc);
        acc = mfma16(kh1, qh1, acc);
        acc = mfma16(kh1, ql1, acc);
        s[t] = acc;
    }

    // ---- row max & min (row = i0+l15, one row per lane) ----
    f32x4 vmx = s[0], vmn = s[0];
    #pragma unroll
    for (int t = 1; t < 16; ++t)
        #pragma unroll
        for (int r = 0; r < 4; ++r) {
            vmx[r] = fmaxf(vmx[r], s[t][r]);
            vmn[r] = fminf(vmn[r], s[t][r]);
        }
    float mx = fmaxf(fmaxf(vmx[0], vmx[1]), fmaxf(vmx[2], vmx[3]));
    float mn = fminf(fminf(vmn[0], vmn[1]), fminf(vmn[2], vmn[3]));
    // reduce across quads (lanes l15, l15+16, l15+32, l15+48 share a row)
    mx = fmaxf(mx, __shfl_xor(mx, 16));  mn = fminf(mn, __shfl_xor(mn, 16));
    mx = fmaxf(mx, __shfl_xor(mx, 32));  mn = fminf(mn, __shfl_xor(mn, 32));

    __shared__ float redmax[8][16], redmin[8][16], redsum[8][16];
    if (lane < 16) { redmax[w][l15] = mx; redmin[w][l15] = mn; }
    __syncthreads();

    float mm = redmax[0][l15], nn = redmin[0][l15];
    #pragma unroll
    for (int ww = 1; ww < 8; ++ww) {
        mm = fmaxf(mm, redmax[ww][l15]);
        nn = fminf(nn, redmin[ww][l15]);
    }
    const float inv = 1.0f / mm;
    // z = qkt/rmax; true max of z = max(1, rmin/rmax) (handles rmax<0)
    const float nz  = -fmaxf(1.0f, nn * inv);

    // ---- exp(z - zmax) in place + row sum ----
    float lsum = 0.f;
    #pragma unroll
    for (int t = 0; t < 16; ++t)
        #pragma unroll
        for (int r = 0; r < 4; ++r) {
            float e = __expf(fmaf(s[t][r], inv, nz));
            s[t][r] = e;
            lsum += e;
        }
    lsum += __shfl_xor(lsum, 16);
    lsum += __shfl_xor(lsum, 32);
    if (lane < 16) redsum[w][l15] = lsum;
    __syncthreads();

    float tot = 0.f;
    #pragma unroll
    for (int ww = 0; ww < 8; ++ww) tot += redsum[ww][l15];
    const float invsum = 1.0f / tot;

    // ---- normalize + vectorized nontemporal store fp32 ----
    float* ob = out + (size_t)bb * M_ * M_ + (size_t)(i0 + l15) * M_;
    #pragma unroll
    for (int t = 0; t < 16; ++t) {
        f32x4 v;
        #pragma unroll
        for (int r = 0; r < 4; ++r) v[r] = s[t][r] * invsum;
        __builtin_nontemporal_store(v, (f32x4*)(ob + (w * 16 + t) * 16 + quad * 4));
    }
}

// ---------------------------------------------------------------------------
extern "C" void kernel_launch(void* const* d_in, const int* in_sizes, int n_in,
                              void* d_out, int out_size, void* d_ws, size_t ws_size,
                              hipStream_t stream)
{
    (void)in_sizes; (void)n_in; (void)out_size; (void)ws_size;
    const float* x   = (const float*)d_in[0];
    const float* qW1 = (const float*)d_in[1];
    const float* qb1 = (const float*)d_in[2];
    const float* qW2 = (const float*)d_in[3];
    const float* qb2 = (const float*)d_in[4];
    const float* kW1 = (const float*)d_in[5];
    const float* kb1 = (const float*)d_in[6];
    const float* kW2 = (const float*)d_in[7];
    const float* kb2 = (const float*)d_in[8];
    short* ws  = (short*)d_ws;
    float* out = (float*)d_out;

    prep_w<<<dim3(128, 4), 256, 0, stream>>>(qW1, kW1, qW2, kW2, ws);
    mlp_kernel<<<dim3(ROWS / 64, 2), 128, 0, stream>>>(x, ws, qb1, kb1, qb2, kb2);
    scores_kernel<<<dim3(2048), 512, 0, stream>>>(ws, out);
}

// Round 4
// 396.343 us; speedup vs baseline: 1.1713x; 1.0471x over previous
//
#include <hip/hip_runtime.h>

// Problem dims
#define B_   16
#define M_   2048
#define D_   128
#define H_   256
#define K_   64
#define ROWS (B_ * M_)   // 32768

typedef short short8 __attribute__((ext_vector_type(8)));
typedef short short4v __attribute__((ext_vector_type(4)));
typedef float f32x4  __attribute__((ext_vector_type(4)));

// ws layout (in short/bf16 elements)
// Q stored hi+lo (removes q-side rounding); K stored hi only (error budget:
// k-rounding alone -> absmax ~5e-3 vs 1.55e-2 threshold, measured r3).
static constexpr size_t OFF_QHI = 0;                           // [ROWS][64]
static constexpr size_t OFF_QLO = (size_t)ROWS * K_;
static constexpr size_t OFF_KHI = 2 * (size_t)ROWS * K_;
static constexpr size_t OFF_W1H = 3 * (size_t)ROWS * K_;       // [2][H_][D_]
static constexpr size_t OFF_W1L = OFF_W1H + 2 * (size_t)D_ * H_;
static constexpr size_t OFF_W2H = OFF_W1L + 2 * (size_t)D_ * H_;  // [2][K_][H_]
static constexpr size_t OFF_W2L = OFF_W2H + 2 * (size_t)H_ * K_;

static __device__ __forceinline__ float bf2f(short u) {
    union { unsigned int u; float f; } c;
    c.u = ((unsigned int)(unsigned short)u) << 16;
    return c.f;
}
static __device__ __forceinline__ short f2bf(float f) {
    union { float f; unsigned int u; } c; c.f = f;
    unsigned int u = c.u + 0x7fffu + ((c.u >> 16) & 1u);   // RNE
    return (short)(u >> 16);
}
static __device__ __forceinline__ void split2(float v, short& hi, short& lo) {
    hi = f2bf(v);
    lo = f2bf(v - bf2f(hi));
}
static __device__ __forceinline__ f32x4 mfma16(short8 a, short8 b, f32x4 c) {
    return __builtin_amdgcn_mfma_f32_16x16x32_bf16(a, b, c, 0, 0, 0);
}

// ---------------------------------------------------------------------------
// k0: transpose + hi/lo split weights (fp32 -> bf16 planes)
// ---------------------------------------------------------------------------
__global__ __launch_bounds__(256) void prep_w(
    const float* __restrict__ qW1, const float* __restrict__ kW1,
    const float* __restrict__ qW2, const float* __restrict__ kW2,
    short* __restrict__ ws)
{
    const int which = blockIdx.y;
    const float* src; short* dhi; short* dlo; int N, Kd;
    if (which == 0)      { src = qW1; dhi = ws + OFF_W1H;            dlo = ws + OFF_W1L;            N = H_; Kd = D_; }
    else if (which == 1) { src = kW1; dhi = ws + OFF_W1H + D_ * H_;  dlo = ws + OFF_W1L + D_ * H_;  N = H_; Kd = D_; }
    else if (which == 2) { src = qW2; dhi = ws + OFF_W2H;            dlo = ws + OFF_W2L;            N = K_; Kd = H_; }
    else                 { src = kW2; dhi = ws + OFF_W2H + H_ * K_;  dlo = ws + OFF_W2L + H_ * K_;  N = K_; Kd = H_; }
    int idx = blockIdx.x * 256 + threadIdx.x;
    if (idx < N * Kd) {
        int n = idx / Kd, k = idx % Kd;
        float v = src[(size_t)k * N + n];   // dst[n][k] = src[k][n]
        short hi, lo; split2(v, hi, lo);
        dhi[idx] = hi; dlo[idx] = lo;
    }
}

// ---------------------------------------------------------------------------
// k1 (R4): block-staged fused MLP. 512-thr block (8 waves), 128 rows/block
// (16 rows/wave). Per H-phase (2 x 128 cols) the block cooperatively stages
// the weight slice into LDS (W1: 2x[128][136], W2: 2x[64][136]; 102 KB,
// 1 block/CU) -> weight fetch traffic 393 MB (R3) -> 98 MB, and all
// main-loop weight reads are ds_read_b128.
//
// h stays ENTIRELY in registers: GEMM1 iteration jt loads W1 rows
// pi(jt,l15) = (jt&3)*32 + (l15>>2)*8 + (jt>>2)*4 + (l15&3)  (bijection),
// so lane (l15,quad) produces exactly h cols kk*32+quad*8+{0..7} with
// kk=jt&3, elems (jt>>2)*4+r — i.e. its own GEMM2 A-frag. No h-LDS, no
// shuffles. W1_s reads use a 64B-granule XOR (ks ^= (row>>3)&1) to keep
// 2-way (free) bank aliasing. Same products in the same order per
// accumulator as the verified R3 kernel -> bitwise-identical numerics;
// absmax must stay 0.004882812.
// ---------------------------------------------------------------------------
__global__ __launch_bounds__(512, 2) void mlp_kernel(
    const float* __restrict__ x,     // [ROWS][128] fp32
    short* __restrict__ ws,
    const float* __restrict__ qb1, const float* __restrict__ kb1,
    const float* __restrict__ qb2, const float* __restrict__ kb2)
{
    const int head = blockIdx.y;
    const short* W1H = ws + OFF_W1H + (size_t)head * (D_ * H_);  // [256][128]
    const short* W1L = ws + OFF_W1L + (size_t)head * (D_ * H_);
    const short* W2H = ws + OFF_W2H + (size_t)head * (H_ * K_);  // [64][256]
    const short* W2L = ws + OFF_W2L + (size_t)head * (H_ * K_);
    const float* b1  = head ? kb1 : qb1;
    const float* b2  = head ? kb2 : qb2;
    short* ohi       = ws + (head ? OFF_KHI : OFF_QHI);          // [ROWS][64]
    short* olo       = ws + OFF_QLO;                             // head 0 only

    const int tid  = threadIdx.x;
    const int w    = tid >> 6;        // wave 0..7
    const int lane = tid & 63;
    const int l15  = lane & 15;
    const int quad = lane >> 4;
    const int r0   = blockIdx.x * 128 + w * 16;   // this wave's 16 rows

    // Staged weight slices for the current phase. Row stride 136 shorts
    // (272 B = 17x16B): row*68 words == row*4 (mod 32) -> l15-consecutive
    // row reads are 2-way (free). W1 reads use the granule XOR (see above)
    // because pi() reads rows {g*8+e} which would otherwise be 4-way.
    __shared__ __align__(16) short w1h_s[128 * 136];
    __shared__ __align__(16) short w1l_s[128 * 136];
    __shared__ __align__(16) short w2h_s[64 * 136];
    __shared__ __align__(16) short w2l_s[64 * 136];

    // ---- A-frags from x: A[m=l15][k=quad*8+j], split hi/lo; float4 loads ----
    short8 ah[4], al[4];
    {
        const float* xrow = x + (size_t)(r0 + l15) * D_ + quad * 8;
        #pragma unroll
        for (int ks = 0; ks < 4; ++ks) {
            float4 v0 = *(const float4*)(xrow + ks * 32);
            float4 v1 = *(const float4*)(xrow + ks * 32 + 4);
            float vv[8] = {v0.x, v0.y, v0.z, v0.w, v1.x, v1.y, v1.z, v1.w};
            #pragma unroll
            for (int j = 0; j < 8; ++j) {
                short hi, lo; split2(vv[j], hi, lo);
                ah[ks][j] = hi; al[ks][j] = lo;
            }
        }
    }

    // GEMM2 accumulators live across both phases
    f32x4 acc2[4];
    #pragma unroll
    for (int j = 0; j < 4; ++j) acc2[j] = f32x4{0.f, 0.f, 0.f, 0.f};

    #pragma unroll
    for (int ph = 0; ph < 2; ++ph) {
        if (ph) __syncthreads();    // all waves done reading prev slice

        // ---- stage this phase's weight slice into LDS ----
        // W1 slice: rows ph*128..+127 of [256][128], both planes.
        #pragma unroll
        for (int k = 0; k < 4; ++k) {
            int chunk = tid + k * 512;          // 0..2047 (128 rows x 16)
            int row = chunk >> 4, ci = chunk & 15;
            int cisw = ci ^ (((row >> 3) & 1) << 2);   // 64B-granule XOR
            const size_t so = (size_t)(ph * 128 + row) * D_ + ci * 8;
            *(short8*)&w1h_s[row * 136 + cisw * 8] = *(const short8*)(W1H + so);
            *(short8*)&w1l_s[row * 136 + cisw * 8] = *(const short8*)(W1L + so);
        }
        // W2 slice: cols ph*128..+127 of [64][256], both planes (no XOR).
        #pragma unroll
        for (int k = 0; k < 2; ++k) {
            int chunk = tid + k * 512;          // 0..1023 (64 rows x 16)
            int row = chunk >> 4, ci = chunk & 15;
            const size_t so = (size_t)row * H_ + ph * 128 + ci * 8;
            *(short8*)&w2h_s[row * 136 + ci * 8] = *(const short8*)(W2H + so);
            *(short8*)&w2l_s[row * 136 + ci * 8] = *(const short8*)(W2L + so);
        }
        __syncthreads();

        // ---- GEMM1 (permuted col order): h stays in registers ----
        short8 gh[4], gl[4];   // GEMM2 A-frags, hi/lo
        #pragma unroll
        for (int jt = 0; jt < 8; ++jt) {
            const int kk   = jt & 3;
            const int half = jt >> 2;
            const int rp   = (kk << 5) + ((l15 >> 2) << 3) + (half << 2) + (l15 & 3);
            const int sw   = (rp >> 3) & 1;
            const int base = rp * 136 + quad * 8;
            f32x4 a0 = {0.f, 0.f, 0.f, 0.f};
            #pragma unroll
            for (int ks = 0; ks < 4; ++ks) {
                const int a = base + (ks ^ sw) * 32;   // logical granule ks
                short8 bh = *(const short8*)&w1h_s[a];
                short8 bl = *(const short8*)&w1l_s[a];
                a0 = mfma16(bh, ah[ks], a0);
                a0 = mfma16(bh, al[ks], a0);
                a0 = mfma16(bl, ah[ks], a0);
            }
            // output col = ph*128 + kk*32 + quad*8 + half*4 + r
            float4 bias4 = *(const float4*)(b1 + ph * 128 + kk * 32 + quad * 8 + half * 4);
            #pragma unroll
            for (int r = 0; r < 4; ++r) {
                float v = a0[r] + ((const float*)&bias4)[r];
                v = v > 0.f ? v : 0.f;
                short hi, lo; split2(v, hi, lo);
                gh[kk][half * 4 + r] = hi;
                gl[kk][half * 4 + r] = lo;
            }
        }

        // ---- GEMM2 partial: contraction cols [ph*128, ph*128+128) ----
        #pragma unroll
        for (int kk = 0; kk < 4; ++kk) {
            #pragma unroll
            for (int jt2 = 0; jt2 < 4; ++jt2) {
                const int a = (jt2 * 16 + l15) * 136 + kk * 32 + quad * 8;
                short8 bh = *(const short8*)&w2h_s[a];
                short8 bl = *(const short8*)&w2l_s[a];
                acc2[jt2] = mfma16(bh, gh[kk], acc2[jt2]);
                acc2[jt2] = mfma16(bh, gl[kk], acc2[jt2]);
                acc2[jt2] = mfma16(bl, gh[kk], acc2[jt2]);
            }
        }
    }

    // ---- GEMM2 epilogue: packed b64 stores ----
    #pragma unroll
    for (int jt2 = 0; jt2 < 4; ++jt2) {
        float4 bias4 = *(const float4*)(b2 + jt2 * 16 + quad * 4);
        const size_t oi = (size_t)(r0 + l15) * K_ + jt2 * 16 + quad * 4;
        if (head == 0) {
            short4v hi4, lo4;
            #pragma unroll
            for (int r = 0; r < 4; ++r) {
                float v = acc2[jt2][r] + ((const float*)&bias4)[r];
                short hi, lo; split2(v, hi, lo);
                hi4[r] = hi; lo4[r] = lo;
            }
            *(short4v*)(ohi + oi) = hi4;
            *(short4v*)(olo + oi) = lo4;
        } else {
            short4v hi4;
            #pragma unroll
            for (int r = 0; r < 4; ++r)
                hi4[r] = f2bf(acc2[jt2][r] + ((const float*)&bias4)[r]);
            *(short4v*)(ohi + oi) = hi4;
        }
    }
}

// ---------------------------------------------------------------------------
// k2: scores + max-division softmax. Block = 512 thr (8 waves), 16 Q-rows.
// 1D grid 2048, XCD-swizzled: xcd = flat&7 serves batches {xcd, xcd+8} only
// -> per-XCD L2 working set ~2 MB (K+Q of 2 batches), L2-resident re-reads.
// __launch_bounds__(512,4): VGPR cap 128 -> 2 blocks/CU so one block's
// store phase overlaps the next block's load/MFMA phase.
//
// OPERAND-SWAPPED MFMA: each lane owns 4 consecutive output columns of one
// row -> f32x4 nt stores + scalar row stats. (R1: neutral vs scalar stores
// -> store-drain-bound, not issue-bound.)
// ---------------------------------------------------------------------------
__global__ __launch_bounds__(512, 4) void scores_kernel(
    const short* __restrict__ ws,
    float* __restrict__ out)          // [B][M][M] fp32
{
    const int flat = blockIdx.x;
    const int xcd  = flat & 7;
    const int slot = flat >> 3;
    const int bb   = (slot & 1) * 8 + xcd;   // batch
    const int i0   = (slot >> 1) * 16;       // Q-row tile
    const int tid  = threadIdx.x;
    const int w    = tid >> 6;        // wave 0..7
    const int lane = tid & 63;
    const int l15  = lane & 15;
    const int quad = lane >> 4;

    const short* Qh = ws + OFF_QHI + (size_t)bb * M_ * K_;
    const short* Ql = ws + OFF_QLO + (size_t)bb * M_ * K_;
    const short* Kh = ws + OFF_KHI + (size_t)bb * M_ * K_;

    // Q B-frags for rows i0..i0+15 (B-operand row = l15 = i offset)
    const size_t qo = (size_t)(i0 + l15) * K_ + quad * 8;
    short8 qh0 = *(const short8*)(Qh + qo);
    short8 qh1 = *(const short8*)(Qh + qo + 32);
    short8 ql0 = *(const short8*)(Ql + qo);
    short8 ql1 = *(const short8*)(Ql + qo + 32);

    // s[t][r] = S[i0+l15][(w*16+t)*16 + quad*4 + r]
    f32x4 s[16];
    #pragma unroll
    for (int t = 0; t < 16; ++t) {
        const int j0 = (w * 16 + t) * 16;
        const size_t ko = (size_t)(j0 + l15) * K_ + quad * 8;
        short8 kh0 = *(const short8*)(Kh + ko);
        short8 kh1 = *(const short8*)(Kh + ko + 32);
        f32x4 acc = {0.f, 0.f, 0.f, 0.f};
        acc = mfma16(kh0, qh0, acc);   // A=K (rows j), B=Q (rows i)
        acc = mfma16(kh0, ql0, acc);
        acc = mfma16(kh1, qh1, acc);
        acc = mfma16(kh1, ql1, acc);
        s[t] = acc;
    }

    // ---- row max & min (row = i0+l15, one row per lane) ----
    f32x4 vmx = s[0], vmn = s[0];
    #pragma unroll
    for (int t = 1; t < 16; ++t)
        #pragma unroll
        for (int r = 0; r < 4; ++r) {
            vmx[r] = fmaxf(vmx[r], s[t][r]);
            vmn[r] = fminf(vmn[r], s[t][r]);
        }
    float mx = fmaxf(fmaxf(vmx[0], vmx[1]), fmaxf(vmx[2], vmx[3]));
    float mn = fminf(fminf(vmn[0], vmn[1]), fminf(vmn[2], vmn[3]));
    // reduce across quads (lanes l15, l15+16, l15+32, l15+48 share a row)
    mx = fmaxf(mx, __shfl_xor(mx, 16));  mn = fminf(mn, __shfl_xor(mn, 16));
    mx = fmaxf(mx, __shfl_xor(mx, 32));  mn = fminf(mn, __shfl_xor(mn, 32));

    __shared__ float redmax[8][16], redmin[8][16], redsum[8][16];
    if (lane < 16) { redmax[w][l15] = mx; redmin[w][l15] = mn; }
    __syncthreads();

    float mm = redmax[0][l15], nn = redmin[0][l15];
    #pragma unroll
    for (int ww = 1; ww < 8; ++ww) {
        mm = fmaxf(mm, redmax[ww][l15]);
        nn = fminf(nn, redmin[ww][l15]);
    }
    const float inv = 1.0f / mm;
    // z = qkt/rmax; true max of z = max(1, rmin/rmax) (handles rmax<0)
    const float nz  = -fmaxf(1.0f, nn * inv);

    // ---- exp(z - zmax) in place + row sum ----
    float lsum = 0.f;
    #pragma unroll
    for (int t = 0; t < 16; ++t)
        #pragma unroll
        for (int r = 0; r < 4; ++r) {
            float e = __expf(fmaf(s[t][r], inv, nz));
            s[t][r] = e;
            lsum += e;
        }
    lsum += __shfl_xor(lsum, 16);
    lsum += __shfl_xor(lsum, 32);
    if (lane < 16) redsum[w][l15] = lsum;
    __syncthreads();

    float tot = 0.f;
    #pragma unroll
    for (int ww = 0; ww < 8; ++ww) tot += redsum[ww][l15];
    const float invsum = 1.0f / tot;

    // ---- normalize + vectorized nontemporal store fp32 ----
    float* ob = out + (size_t)bb * M_ * M_ + (size_t)(i0 + l15) * M_;
    #pragma unroll
    for (int t = 0; t < 16; ++t) {
        f32x4 v;
        #pragma unroll
        for (int r = 0; r < 4; ++r) v[r] = s[t][r] * invsum;
        __builtin_nontemporal_store(v, (f32x4*)(ob + (w * 16 + t) * 16 + quad * 4));
    }
}

// ---------------------------------------------------------------------------
extern "C" void kernel_launch(void* const* d_in, const int* in_sizes, int n_in,
                              void* d_out, int out_size, void* d_ws, size_t ws_size,
                              hipStream_t stream)
{
    (void)in_sizes; (void)n_in; (void)out_size; (void)ws_size;
    const float* x   = (const float*)d_in[0];
    const float* qW1 = (const float*)d_in[1];
    const float* qb1 = (const float*)d_in[2];
    const float* qW2 = (const float*)d_in[3];
    const float* qb2 = (const float*)d_in[4];
    const float* kW1 = (const float*)d_in[5];
    const float* kb1 = (const float*)d_in[6];
    const float* kW2 = (const float*)d_in[7];
    const float* kb2 = (const float*)d_in[8];
    short* ws  = (short*)d_ws;
    float* out = (float*)d_out;

    prep_w<<<dim3(128, 4), 256, 0, stream>>>(qW1, kW1, qW2, kW2, ws);
    mlp_kernel<<<dim3(ROWS / 128, 2), 512, 0, stream>>>(x, ws, qb1, kb1, qb2, kb2);
    scores_kernel<<<dim3(2048), 512, 0, stream>>>(ws, out);
}